// Round 18
// baseline (259.508 us; speedup 1.0000x reference)
//
#include <hip/hip_runtime.h>
#include <math.h>

namespace {

constexpr int       kNME    = 262144;
constexpr int       kNDOF   = 524288;
constexpr long long kNNZ    = 16777216;   // kNME * 64
constexpr int       kNB     = 64;         // buckets
constexpr int       kBShift = 13;         // 8192 dofs / bucket
constexpr int       kBSpan  = 8192;
constexpr int       kEnt    = 8192;       // entries per producer block
constexpr int       kPTh    = 1024;       // block threads (both roles)
constexpr int       kPerTh  = 8;          // kEnt / kPTh
constexpr int       kCtrStride = 16;      // counters padded to 64 B
constexpr int       kScaleBlocks = kNME / 256;   // 1024
constexpr int       kR      = 8;          // sub-regions per bucket
constexpr long long kChunk  = kNNZ / 2;   // 8388608 entries per chunk
constexpr int       kPBlk   = (int)(kChunk / kEnt);   // 1024 producer blocks
constexpr int       kCBlk   = kNB * kR;               // 512 consumer blocks

constexpr float kEmin    = 1e-9f;
constexpr float kEmax    = 1.0f;
constexpr float kVolfrac = 0.4f;

using u32   = unsigned;
using i32x4 = __attribute__((ext_vector_type(4))) int;
using f32x4 = __attribute__((ext_vector_type(4))) float;
using u32x4 = __attribute__((ext_vector_type(4))) unsigned;

// pair = (localrow:13 bits << 19) | (fp32 bits >> 13)  [sign+exp+10 mantissa]
__device__ __forceinline__ u32 pack32(unsigned localrow, float v) {
    return (localrow << 19) | (__float_as_uint(v) >> 13);
}

// ---------------------------------------------------------------------------
// Producer body (round-17 exact mechanics).  pidx = logical block in chunk.
// ---------------------------------------------------------------------------
__device__ __forceinline__ void producer_body(
    const float* __restrict__ K_sep, const int* __restrict__ rows,
    const int* __restrict__ cols, const float* __restrict__ u,
    const float* __restrict__ scale, u32* __restrict__ pairs,
    unsigned* __restrict__ counters, long long chunk_base,
    unsigned capSub, int pidx,
    unsigned* hist, unsigned* ofs, unsigned* gbase, u32* sorted) {
    const int tid = threadIdx.x;
    const int sub = pidx & (kR - 1);
    if (tid < kNB) hist[tid] = 0u;
    __syncthreads();

    const long long i0 =
        chunk_base + (long long)pidx * kEnt + (long long)tid * kPerTh;
    i32x4 r0 = __builtin_nontemporal_load((const i32x4*)(rows + i0));
    i32x4 r1 = __builtin_nontemporal_load((const i32x4*)(rows + i0) + 1);
    i32x4 c0 = __builtin_nontemporal_load((const i32x4*)(cols + i0));
    i32x4 c1 = __builtin_nontemporal_load((const i32x4*)(cols + i0) + 1);
    f32x4 k0 = __builtin_nontemporal_load((const f32x4*)(K_sep + i0));
    f32x4 k1 = __builtin_nontemporal_load((const f32x4*)(K_sep + i0) + 1);
    const float s = scale[(int)(i0 >> 6)];   // all 8 share one element

    unsigned rv[kPerTh];
    float    vv[kPerTh];
#pragma unroll
    for (int j = 0; j < 4; ++j) {
        rv[j]     = (unsigned)r0[j];  vv[j]     = k0[j] * s * u[c0[j]];
        rv[j + 4] = (unsigned)r1[j];  vv[j + 4] = k1[j] * s * u[c1[j]];
    }
#pragma unroll
    for (int j = 0; j < kPerTh; ++j)
        rv[j] |= atomicAdd(&hist[rv[j] >> kBShift], 1u) << 19;
    __syncthreads();

    if (tid < kNB) {
        unsigned h = hist[tid];
        unsigned x = h;
#pragma unroll
        for (int off = 1; off < kNB; off <<= 1) {
            unsigned y = __shfl_up(x, off, 64);
            if (tid >= off) x += y;
        }
        ofs[tid]   = x - h;
        gbase[tid] = atomicAdd(&counters[(tid * kR + sub) * kCtrStride], h);
    }
    __syncthreads();

#pragma unroll
    for (int j = 0; j < kPerTh; ++j) {
        unsigned row = rv[j] & 0x7FFFFu;
        unsigned b   = row >> kBShift;
        unsigned pos = ofs[b] + (rv[j] >> 19);
        sorted[pos]  = pack32(row & (kBSpan - 1), vv[j]);
    }
    __syncthreads();

    const int wid = tid >> 6, lane = tid & 63;
    for (int b = wid; b < kNB; b += 16) {
        const unsigned s0 = ofs[b];
        const unsigned n  = hist[b];
        const unsigned g  = gbase[b];
        u32* dst = pairs + (size_t)(b * kR + sub) * capSub + g;
        for (unsigned i = lane; i < n; i += 64) {
            if (g + i < capSub) dst[i] = sorted[s0 + i];
        }
    }
}

// ---------------------------------------------------------------------------
// Consumer body (round-17 exact mechanics).  cidx = (b, sub); 1024 threads.
// ---------------------------------------------------------------------------
__device__ __forceinline__ void consumer_body(
    const u32* __restrict__ pairs, const unsigned* __restrict__ counters,
    float* __restrict__ partial, unsigned capSub, int cidx, int accum,
    float* acc) {
    const int b   = cidx / kR;
    const int sub = cidx - b * kR;
    unsigned cnt = counters[(b * kR + sub) * kCtrStride];
    if (cnt > capSub) cnt = capSub;

    for (int i = threadIdx.x; i < kBSpan; i += kPTh) acc[i] = 0.0f;
    __syncthreads();

    const u32* p = pairs + (size_t)(b * kR + sub) * capSub;
    const unsigned aligned = cnt & ~3u;
    for (unsigned i = 4 * threadIdx.x; i < aligned; i += 4 * kPTh) {
        u32x4 e = *((const u32x4*)(p + i));
#pragma unroll
        for (int j = 0; j < 4; ++j)
            atomicAdd(&acc[e[j] >> 19], __uint_as_float(e[j] << 13));
    }
    if (threadIdx.x < (cnt - aligned)) {
        u32 e = p[aligned + threadIdx.x];
        atomicAdd(&acc[e >> 19], __uint_as_float(e << 13));
    }
    __syncthreads();

    float* dst = partial + (size_t)(b * kR + sub) * kBSpan;
    if (accum) {
        for (int k = threadIdx.x; k < kBSpan; k += kPTh) dst[k] += acc[k];
    } else {
        for (int k = threadIdx.x; k < kBSpan; k += kPTh) dst[k] = acc[k];
    }
}

// ---------------------------------------------------------------------------
// Kernel 1: SIMP scale + workspace init (zeroes BOTH counter sets).
// ---------------------------------------------------------------------------
__global__ void scale_kernel(const float* __restrict__ W_x,
                             float* __restrict__ scale,
                             float* __restrict__ acc,       // [16]
                             unsigned* __restrict__ counters, // [2 sets]
                             float* __restrict__ rho_part) {
    const int gid = blockIdx.x * blockDim.x + threadIdx.x;

    if (gid >= 1 && gid < 16) acc[gid] = 0.0f;
    const int cidx = gid - 16;
    if (cidx >= 0 && cidx < 2 * kNB * kR * kCtrStride) counters[cidx] = 0u;

    float rho = 0.0f;
    if (gid < kNME) {
        float x = W_x[gid];
        rho = 1.0f / (1.0f + __expf(-x));
        scale[gid] = kEmin + rho * rho * rho * (kEmax - kEmin);
    }
    for (int off = 32; off > 0; off >>= 1) rho += __shfl_down(rho, off, 64);
    __shared__ float partial[4];
    const int lane = threadIdx.x & 63;
    const int wid  = threadIdx.x >> 6;
    if (lane == 0) partial[wid] = rho;
    __syncthreads();
    if (threadIdx.x == 0)
        rho_part[blockIdx.x] =
            partial[0] + partial[1] + partial[2] + partial[3];
}

// ---------------------------------------------------------------------------
// Node 2: pure producer, chunk 0.
// ---------------------------------------------------------------------------
__global__ __launch_bounds__(kPTh, 8)
void p0_kernel(const float* __restrict__ K_sep, const int* __restrict__ rows,
               const int* __restrict__ cols, const float* __restrict__ u,
               const float* __restrict__ scale, u32* __restrict__ pairs0,
               unsigned* __restrict__ ctr0, unsigned capSub) {
    __shared__ unsigned hist[kNB], ofs[kNB], gbase[kNB];
    __shared__ __align__(16) u32 sorted[kEnt];
    producer_body(K_sep, rows, cols, u, scale, pairs0, ctr0, 0LL, capSub,
                  blockIdx.x, hist, ofs, gbase, sorted);
}

// ---------------------------------------------------------------------------
// Node 3: MIXED — producer chunk 1 (1024 blocks) || consumer chunk 0
// (512 blocks).  Interleaved 2:1 in dispatch order so both roles co-reside.
// ---------------------------------------------------------------------------
__global__ __launch_bounds__(kPTh, 8)
void p1c0_kernel(const float* __restrict__ K_sep, const int* __restrict__ rows,
                 const int* __restrict__ cols, const float* __restrict__ u,
                 const float* __restrict__ scale,
                 u32* __restrict__ pairs0, u32* __restrict__ pairs1,
                 unsigned* __restrict__ ctr0, unsigned* __restrict__ ctr1,
                 float* __restrict__ partial, unsigned capSub) {
    __shared__ unsigned hist[kNB], ofs[kNB], gbase[kNB];
    __shared__ __align__(16) u32 sorted[kEnt];   // consumer reuses as f32 acc

    const int i = blockIdx.x;          // 0 .. 1535
    if ((i % 3) != 2) {
        const int pidx = (i / 3) * 2 + (i % 3);     // 0..1023
        producer_body(K_sep, rows, cols, u, scale, pairs1, ctr1, kChunk,
                      capSub, pidx, hist, ofs, gbase, sorted);
    } else {
        const int cidx = i / 3;                     // 0..511
        consumer_body(pairs0, ctr0, partial, capSub, cidx, /*accum=*/0,
                      (float*)sorted);
    }
}

// ---------------------------------------------------------------------------
// Node 4: pure consumer, chunk 1 (accumulates into the planes).
// ---------------------------------------------------------------------------
__global__ __launch_bounds__(kPTh, 8)
void c1_kernel(const u32* __restrict__ pairs1, const unsigned* __restrict__ ctr1,
               float* __restrict__ partial, unsigned capSub) {
    __shared__ __align__(16) float acc[kBSpan];
    consumer_body(pairs1, ctr1, partial, capSub, blockIdx.x, /*accum=*/1, acc);
}

// ---------------------------------------------------------------------------
// Node 5: norm + finalize (round-17 exact).
// ---------------------------------------------------------------------------
__global__ void norm_kernel(const float* __restrict__ partial,
                            const float* __restrict__ f,
                            float* __restrict__ acc,
                            const float* __restrict__ rho_part,
                            float* __restrict__ out) {
    const int b  = blockIdx.x >> 3;
    const int i0 = (blockIdx.x & 7) * 1024 + threadIdx.x * 4;
    f32x4 s = {0.0f, 0.0f, 0.0f, 0.0f};
#pragma unroll
    for (int r = 0; r < kR; ++r)
        s += *(const f32x4*)(partial + (size_t)(b * kR + r) * kBSpan + i0);
    f32x4 fv = *(const f32x4*)(f + (size_t)b * kBSpan + i0);
    f32x4 d  = s - fv;
    float a = d[0] * d[0] + d[1] * d[1] + d[2] * d[2] + d[3] * d[3];
    for (int off = 32; off > 0; off >>= 1) a += __shfl_down(a, off, 64);
    __shared__ float partial_s[4];
    const int lane = threadIdx.x & 63;
    const int wid  = threadIdx.x >> 6;
    if (lane == 0) partial_s[wid] = a;
    __syncthreads();
    if (threadIdx.x == 0) {
        atomicAdd(&acc[1],
                  partial_s[0] + partial_s[1] + partial_s[2] + partial_s[3]);
        __threadfence();
        unsigned done = atomicAdd((unsigned*)&acc[2], 1u);
        if (done == gridDim.x - 1) {
            float rs = 0.0f;
            for (int i = 0; i < kScaleBlocks; i += 4) {
                f32x4 rp = *(const f32x4*)(rho_part + i);
                rs += rp[0] + rp[1] + rp[2] + rp[3];
            }
            float ns = __hip_atomic_load(&acc[1], __ATOMIC_RELAXED,
                                         __HIP_MEMORY_SCOPE_AGENT);
            float rho_mean = rs * (1.0f / (float)kNME);
            out[0] = fmaxf(rho_mean - kVolfrac, 0.0f) + sqrtf(ns);
        }
    }
}

// ---------------------------------------------------------------------------
// Fallback path (device atomics) if workspace is too small.
// ---------------------------------------------------------------------------
__global__ void scale1_kernel(const float* __restrict__ W_x,
                              float* __restrict__ scale,
                              float* __restrict__ rho_sum) {
    int i = blockIdx.x * blockDim.x + threadIdx.x;
    float rho = 0.0f;
    if (i < kNME) {
        float x = W_x[i];
        rho = 1.0f / (1.0f + __expf(-x));
        scale[i] = kEmin + rho * rho * rho * (kEmax - kEmin);
    }
    for (int off = 32; off > 0; off >>= 1) rho += __shfl_down(rho, off, 64);
    __shared__ float partial[4];
    const int lane = threadIdx.x & 63;
    const int wid  = threadIdx.x >> 6;
    if (lane == 0) partial[wid] = rho;
    __syncthreads();
    if (threadIdx.x == 0)
        atomicAdd(rho_sum, partial[0] + partial[1] + partial[2] + partial[3]);
}

__global__ void scatter_dev_kernel(const float* __restrict__ K_sep,
                                   const int*   __restrict__ rows,
                                   const int*   __restrict__ cols,
                                   const float* __restrict__ u,
                                   const float* __restrict__ scale,
                                   float* __restrict__ Ku) {
    long long i = (long long)blockIdx.x * blockDim.x + threadIdx.x;
    if (i >= kNNZ) return;
    float s = scale[(int)(i >> 6)];
    atomicAdd(&Ku[rows[i]], K_sep[i] * s * u[cols[i]]);
}

__global__ void norm1_kernel(const float* __restrict__ Ku,
                             const float* __restrict__ f,
                             float* __restrict__ norm_sum) {
    float a = 0.0f;
    for (int i = blockIdx.x * blockDim.x + threadIdx.x; i < kNDOF;
         i += gridDim.x * blockDim.x) {
        float d = Ku[i] - f[i];
        a += d * d;
    }
    for (int off = 32; off > 0; off >>= 1) a += __shfl_down(a, off, 64);
    __shared__ float partial_s[4];
    const int lane = threadIdx.x & 63;
    const int wid  = threadIdx.x >> 6;
    if (lane == 0) partial_s[wid] = a;
    __syncthreads();
    if (threadIdx.x == 0)
        atomicAdd(norm_sum,
                  partial_s[0] + partial_s[1] + partial_s[2] + partial_s[3]);
}

__global__ void finalize_kernel(const float* __restrict__ acc,
                                float* __restrict__ out) {
    if (threadIdx.x == 0 && blockIdx.x == 0) {
        float rho_mean = acc[0] * (1.0f / (float)kNME);
        float vol = fmaxf(rho_mean - kVolfrac, 0.0f);
        out[0] = vol + sqrtf(acc[1]);
    }
}

}  // namespace

extern "C" void kernel_launch(void* const* d_in, const int* in_sizes, int n_in,
                              void* d_out, int out_size, void* d_ws, size_t ws_size,
                              hipStream_t stream) {
    const float* W_x   = (const float*)d_in[0];
    const float* K_sep = (const float*)d_in[1];
    const int*   idx   = (const int*)d_in[2];
    const float* u     = (const float*)d_in[3];
    const float* f     = (const float*)d_in[4];
    const int* rows = idx;
    const int* cols = idx + kNNZ;

    float* ws = (float*)d_ws;
    const size_t avail = ws_size / sizeof(float);

    // Chunked config: per-chunk capSub mean 16384 + 2048 margin.
    const unsigned capSub = (unsigned)(kChunk / (kNB * kR)) + 2048;  // 18432
    const size_t   ctrF   = (size_t)kNB * kR * kCtrStride;           // 8192/set
    const size_t   headF  = 16;
    const size_t   rhoF   = kScaleBlocks;                            // 1024
    const size_t   partF  = (size_t)kNB * kR * kBSpan;               // 4.2M
    const size_t   pairF  = (size_t)kNB * kR * capSub;               // per chunk
    const size_t   need   = headF + 2 * ctrF + rhoF + partF + kNME +
                            2 * pairF;

    if (need > avail) {
        // Fallback: device-atomic scatter (fits in ~3.2 MB).
        float* Ku    = ws;
        float* scale = ws + kNDOF;
        float* acc   = ws + kNDOF + kNME;
        hipMemsetAsync(ws, 0, (size_t)(kNDOF + kNME + 16) * sizeof(float), stream);
        scale1_kernel<<<kNME / 256, 256, 0, stream>>>(W_x, scale, acc);
        scatter_dev_kernel<<<(int)(kNNZ / 256), 256, 0, stream>>>(
            K_sep, rows, cols, u, scale, Ku);
        norm1_kernel<<<2048, 256, 0, stream>>>(Ku, f, acc + 1);
        finalize_kernel<<<1, 64, 0, stream>>>(acc, (float*)d_out);
        return;
    }

    float*    acc      = ws;                          // [16] norm@1, done@2
    unsigned* ctr0     = (unsigned*)(ws + headF);     // [ctrF]
    unsigned* ctr1     = ctr0 + ctrF;                 // [ctrF]
    float*    rho_part = ws + headF + 2 * ctrF;       // [kScaleBlocks]
    float*    partial  = rho_part + rhoF;             // [kNB*kR*kBSpan]
    float*    scale    = partial + partF;             // [kNME]
    u32*      pairs0   = (u32*)(scale + kNME);        // [pairF]
    u32*      pairs1   = pairs0 + pairF;              // [pairF]

    // Node 1: scale + init (zeroes both counter sets).
    scale_kernel<<<kScaleBlocks, 256, 0, stream>>>(W_x, scale, acc, ctr0,
                                                   rho_part);

    // Node 2: producer chunk 0.
    p0_kernel<<<kPBlk, kPTh, 0, stream>>>(K_sep, rows, cols, u, scale,
                                          pairs0, ctr0, capSub);

    // Node 3: producer chunk 1 || consumer chunk 0 (2:1 interleaved).
    p1c0_kernel<<<kPBlk + kCBlk, kPTh, 0, stream>>>(
        K_sep, rows, cols, u, scale, pairs0, pairs1, ctr0, ctr1, partial,
        capSub);

    // Node 4: consumer chunk 1 (accumulate).
    c1_kernel<<<kCBlk, kPTh, 0, stream>>>(pairs1, ctr1, partial, capSub);

    // Node 5: norm + finalize.
    norm_kernel<<<kNB * (kBSpan / 1024), 256, 0, stream>>>(
        partial, f, acc, rho_part, (float*)d_out);
}